// Round 7
// baseline (907.765 us; speedup 1.0000x reference)
//
#include <hip/hip_runtime.h>
#include <hip/hip_bf16.h>

typedef __attribute__((ext_vector_type(8))) __bf16 bf16x8;
typedef __attribute__((ext_vector_type(4))) __bf16 bf16x4;
typedef __attribute__((ext_vector_type(4))) float f32x4;

#define B_ROWS 16384
#define LDF 2560
#define BN_EPS 1e-5f
#define PLANE ((size_t)256 * 128 * 128)  // floats per sk-plane (256 tiles x 16384)

__device__ __forceinline__ void async16(void* lds, const void* g) {
  __builtin_amdgcn_global_load_lds(
      (const __attribute__((address_space(1))) unsigned int*)g,
      (__attribute__((address_space(3))) unsigned int*)lds, 16, 0, 0);
}

__device__ __forceinline__ bf16x8 cvt8(float4 a, float4 b) {
  bf16x8 t;
  t[0] = (__bf16)a.x; t[1] = (__bf16)a.y; t[2] = (__bf16)a.z; t[3] = (__bf16)a.w;
  t[4] = (__bf16)b.x; t[5] = (__bf16)b.y; t[6] = (__bf16)b.z; t[7] = (__bf16)b.w;
  return t;
}

// Split-K GEMM with fused last-finisher reduction + epilogue.
// Tile 128x128, BK=32, 4 waves (2x2), wave-tile 64x64, acc 4x4.
// 4-buffer LDS (64KB -> 2 blocks/CU, grid 512 all-resident), counted vmcnt.
// wgid = tile*SK + sk (sk partners same XCD chunk). Roles: first SK-1 finishers
// write partial planes; last finisher combines (fixed sk order) + epilogue.
// mode 1: relu+stats -> bf16 hout (stride LDF). mode 0: fp32 fout (ldc=128) + badj.
__global__ __launch_bounds__(256) void gemm_fused(
    const __bf16* __restrict__ A, const __bf16* __restrict__ W,
    float* __restrict__ Cpart, const float* __restrict__ badj,
    __bf16* __restrict__ hout, float* __restrict__ fout,
    float* __restrict__ colsum, float* __restrict__ colsumsq,
    int* __restrict__ flags,
    int Kd, int Ksplit, int mode, int bxbits, int skbits)
{
  __shared__ __bf16 lds[4][256 * 32];
  __shared__ int s_role;

  const int tid  = threadIdx.x;
  const int lane = tid & 63;
  const int wid  = tid >> 6;
  const int wm   = wid >> 1, wn = wid & 1;
  const int fr   = lane & 15, fk = lane >> 4;

  const int cpx  = gridDim.x >> 3;
  const int wgid = (blockIdx.x & 7) * cpx + (blockIdx.x >> 3);
  const int SK   = 1 << skbits;
  const int sk   = wgid & (SK - 1);
  const int tile = wgid >> skbits;
  const int bx   = tile & ((1 << bxbits) - 1);
  const int by   = tile >> bxbits;
  const int bn0  = bx * 128, bm0 = by * 128;
  const int k0   = sk * Ksplit;

  // staging: group j rows j*64+(tid>>2); source k-chunk pre-swizzled.
  const int srow = tid >> 2;
  const int sko  = ((tid & 3) ^ ((tid >> 3) & 3)) << 3;
  const __bf16* a0p = A + (size_t)(bm0 + srow) * LDF + k0 + sko;
  const __bf16* a1p = a0p + (size_t)64 * LDF;
  const __bf16* b0p = W + (size_t)(bn0 + srow) * Kd + k0 + sko;
  const __bf16* b1p = b0p + (size_t)64 * Kd;

#define STAGE(b, kt) do {                                           \
    async16((void*)(&lds[b][(size_t)tid * 8]),         a0p + (kt)); \
    async16((void*)(&lds[b][(size_t)(256 + tid) * 8]), a1p + (kt)); \
    async16((void*)(&lds[b][(size_t)(512 + tid) * 8]), b0p + (kt)); \
    async16((void*)(&lds[b][(size_t)(768 + tid) * 8]), b1p + (kt)); \
  } while (0)

  int aoff[4], boff[4];
#pragma unroll
  for (int i = 0; i < 4; ++i) {
    int ra = wm * 64 + i * 16 + fr;
    aoff[i] = ra * 32 + ((fk ^ ((ra >> 1) & 3)) << 3);
    int rb = wn * 64 + i * 16 + fr;
    boff[i] = 4096 + rb * 32 + ((fk ^ ((rb >> 1) & 3)) << 3);
  }

  f32x4 acc[4][4] = {};

  const int NT = Ksplit >> 5;
  STAGE(0, 0);
  STAGE(1, 32);
  STAGE(2, 64);

  for (int t = 0; t < NT; ++t) {
    if (t <= NT - 3)      asm volatile("s_waitcnt vmcnt(8)" ::: "memory");
    else if (t == NT - 2) asm volatile("s_waitcnt vmcnt(4)" ::: "memory");
    else                  asm volatile("s_waitcnt vmcnt(0)" ::: "memory");
    __builtin_amdgcn_s_barrier();
    __builtin_amdgcn_sched_barrier(0);

    if (t + 3 < NT) STAGE((t + 3) & 3, (t + 3) * 32);
    __builtin_amdgcn_sched_barrier(0);

    const __bf16* bp = lds[t & 3];
    bf16x8 af[4], bf[4];
#pragma unroll
    for (int i = 0; i < 4; ++i) af[i] = *(const bf16x8*)(bp + aoff[i]);
#pragma unroll
    for (int i = 0; i < 4; ++i) bf[i] = *(const bf16x8*)(bp + boff[i]);
#pragma unroll
    for (int mi = 0; mi < 4; ++mi)
#pragma unroll
      for (int ni = 0; ni < 4; ++ni)
        acc[mi][ni] = __builtin_amdgcn_mfma_f32_16x16x32_bf16(af[mi], bf[ni], acc[mi][ni], 0, 0, 0);
  }
#undef STAGE

  // ---- role assignment (first SK-1 finishers = writers, last = reducer) ----
  if (tid == 0) s_role = atomicAdd(&flags[tile], 1);
  __syncthreads();
  const int role = s_role;

  float* tbase = Cpart + (size_t)tile * 16384;

  if (role != SK - 1) {
    // writer: store own partial plane, release.
    float* cp = tbase + (size_t)sk * PLANE;
#pragma unroll
    for (int mi = 0; mi < 4; ++mi)
#pragma unroll
      for (int ni = 0; ni < 4; ++ni) {
        const int rl = wm * 64 + mi * 16 + fk * 4;
        const int cl = wn * 64 + ni * 16 + fr;
#pragma unroll
        for (int r = 0; r < 4; ++r)
          cp[(size_t)(rl + r) * 128 + cl] = acc[mi][ni][r];
      }
    __threadfence();
    __syncthreads();
    if (tid == 0)
      __hip_atomic_fetch_add(&flags[tile], 4, __ATOMIC_RELEASE, __HIP_MEMORY_SCOPE_AGENT);
    return;
  }

  // reducer: wait for all writers (acquire invalidates this CU's L1).
  if (tid == 0) {
    const int target = SK + (SK - 1) * 4;
    while (__hip_atomic_load(&flags[tile], __ATOMIC_ACQUIRE, __HIP_MEMORY_SCOPE_AGENT) < target)
      __builtin_amdgcn_s_sleep(2);
  }
  __syncthreads();

  float psum[4] = {0.f, 0.f, 0.f, 0.f}, psq[4] = {0.f, 0.f, 0.f, 0.f};
#pragma unroll
  for (int mi = 0; mi < 4; ++mi) {
#pragma unroll
    for (int ni = 0; ni < 4; ++ni) {
      const int rl = wm * 64 + mi * 16 + fk * 4;
      const int cl = wn * 64 + ni * 16 + fr;
      const float* pb = tbase + (size_t)rl * 128 + cl;
      // combine in fixed sk order (deterministic sum)
      float t0 = 0.f, t1 = 0.f, t2 = 0.f, t3 = 0.f;
      for (int s = 0; s < SK; ++s) {
        if (s == sk) {
          t0 += acc[mi][ni][0]; t1 += acc[mi][ni][1];
          t2 += acc[mi][ni][2]; t3 += acc[mi][ni][3];
        } else {
          const float* p = pb + (size_t)s * PLANE;
          t0 += p[0]; t1 += p[128]; t2 += p[256]; t3 += p[384];
        }
      }
      if (mode) {
        const int col = bn0 + cl;
        const float bv = badj[col];
        float v0 = fmaxf(t0 + bv, 0.f), v1 = fmaxf(t1 + bv, 0.f);
        float v2 = fmaxf(t2 + bv, 0.f), v3 = fmaxf(t3 + bv, 0.f);
        psum[ni] += v0 + v1 + v2 + v3;
        psq[ni]  += v0 * v0 + v1 * v1 + v2 * v2 + v3 * v3;
        __bf16* hp = hout + (size_t)(bm0 + rl) * LDF + col;
        hp[0] = (__bf16)v0; hp[LDF] = (__bf16)v1;
        hp[2 * LDF] = (__bf16)v2; hp[3 * LDF] = (__bf16)v3;
      } else {
        const float bv = badj[cl];
        float* fp = fout + (size_t)(bm0 + rl) * 128 + cl;
        fp[0] = t0 + bv; fp[128] = t1 + bv;
        fp[256] = t2 + bv; fp[384] = t3 + bv;
      }
    }
  }

  if (mode) {
#pragma unroll
    for (int ni = 0; ni < 4; ++ni) {
      float s = psum[ni], q = psq[ni];
      s += __shfl_xor(s, 16); s += __shfl_xor(s, 32);
      q += __shfl_xor(q, 16); q += __shfl_xor(q, 32);
      if (fk == 0) {
        int col = bn0 + wn * 64 + ni * 16 + fr;
        atomicAdd(&colsum[col], s);
        atomicAdd(&colsumsq[col], q);
      }
    }
  }
}

__global__ void cast_x_kernel(const float* __restrict__ x, __bf16* __restrict__ feats) {
  int idx = blockIdx.x * blockDim.x + threadIdx.x;  // B_ROWS*64 threads
  int row = idx >> 6, c8 = (idx & 63) << 3;
  const float4* xp = (const float4*)(x + (size_t)row * 512 + c8);
  float4 a = xp[0], b = xp[1];
  *(bf16x8*)(feats + (size_t)row * LDF + c8) = cvt8(a, b);
}

// Fused fp32->bf16 W-cast with BN folded: W'[n,c]=W[n,c]*sc[c]; badj[n]=bias[n]+sum_c sh[c]*W[n,c]
__global__ void prep_w(const float* __restrict__ W, const float* __restrict__ bias,
                       const float* __restrict__ colsum, const float* __restrict__ colsumsq,
                       const float* __restrict__ gamma, const float* __restrict__ beta,
                       __bf16* __restrict__ Wb, float* __restrict__ badj, int Kd)
{
  const int n = blockIdx.x, t = threadIdx.x;  // 256 threads per row
  const float invB = 1.0f / 16384.0f;
  float accb = 0.f;
  for (int c0 = t * 4; c0 < Kd; c0 += 1024) {
    float4 w = *(const float4*)(W + (size_t)n * Kd + c0);
    float wv[4] = {w.x, w.y, w.z, w.w};
    bf16x4 o;
#pragma unroll
    for (int i = 0; i < 4; ++i) {
      int c = c0 + i;
      float sc = 1.f, sh = 0.f;
      if (c >= 512) {
        int idx = c - 512;
        float mu  = colsum[idx] * invB;
        float var = colsumsq[idx] * invB - mu * mu;
        sc = gamma[idx] * rsqrtf(var + BN_EPS);
        sh = beta[idx] - mu * sc;
      }
      accb += wv[i] * sh;
      o[i] = (__bf16)(wv[i] * sc);
    }
    *(bf16x4*)(Wb + (size_t)n * Kd + c0) = o;
  }
  __shared__ float red[256];
  red[t] = accb;
  __syncthreads();
  for (int s = 128; s > 0; s >>= 1) {
    if (t < s) red[t] += red[t + s];
    __syncthreads();
  }
  if (t == 0) badj[n] = bias[n] + red[0];
}

extern "C" void kernel_launch(void* const* d_in, const int* in_sizes, int n_in,
                              void* d_out, int out_size, void* d_ws, size_t ws_size,
                              hipStream_t stream) {
  const float* x = (const float*)d_in[0];
  const float* Wi[8];
  for (int i = 0; i < 8; ++i) Wi[i] = (const float*)d_in[1 + i];
  const float* b     = (const float*)d_in[9];
  const float* gamma = (const float*)d_in[10];
  const float* beta  = (const float*)d_in[11];
  const float* Wout  = (const float*)d_in[12];
  const float* bout  = (const float*)d_in[13];
  float* out = (float*)d_out;

  char* ws = (char*)d_ws;
  __bf16* feats = (__bf16*)ws;
  size_t off = (size_t)B_ROWS * LDF * 2;
  __bf16* wb[8];
  {
    int d = 512;
    for (int i = 0; i < 8; ++i) { wb[i] = (__bf16*)(ws + off); off += (size_t)256 * d * 2; d += 256; }
  }
  __bf16* woutb = (__bf16*)(ws + off); off += (size_t)128 * 2560 * 2;
  float* Cpart = (float*)(ws + off); off += 4 * PLANE * 4;  // 67 MB
  float* colsum   = (float*)(ws + off); off += 8 * 256 * 4;
  float* colsumsq = (float*)(ws + off); off += 8 * 256 * 4;
  int*   flags    = (int*)(ws + off);   off += 9 * 256 * 4;
  float* badj     = (float*)(ws + off); off += 9 * 256 * 4;

  // zero colsum + colsumsq + flags (contiguous)
  hipMemsetAsync(colsum, 0, (8 * 256 * 2 + 9 * 256) * 4, stream);

  cast_x_kernel<<<B_ROWS * 64 / 256, 256, 0, stream>>>(x, feats);

  int d = 512;
  for (int i = 0; i < 8; ++i) {
    prep_w<<<256, 256, 0, stream>>>(Wi[i], b + i * 256, colsum, colsumsq,
                                    gamma, beta, wb[i], badj + i * 256, d);
    // SK=2: grid = 128 by * 2 bx * 2 sk = 512 (all-resident at 2 blocks/CU)
    gemm_fused<<<512, 256, 0, stream>>>(feats, wb[i], Cpart, badj + i * 256,
                                        feats + d, nullptr,
                                        colsum + i * 256, colsumsq + i * 256,
                                        flags + i * 256, d, d / 2, 1, 1, 1);
    d += 256;
  }
  prep_w<<<128, 256, 0, stream>>>(Wout, bout, colsum, colsumsq,
                                  gamma, beta, woutb, badj + 8 * 256, 2560);
  // final: bxbits=0, SK=4: grid = 128 * 1 * 4 = 512
  gemm_fused<<<512, 256, 0, stream>>>(feats, woutb, Cpart, badj + 8 * 256,
                                      nullptr, out, nullptr, nullptr,
                                      flags + 8 * 256, 2560, 640, 0, 0, 2);
}

// Round 9
// 495.357 us; speedup vs baseline: 1.8325x; 1.8325x over previous
//
#include <hip/hip_runtime.h>
#include <hip/hip_bf16.h>

typedef __attribute__((ext_vector_type(8))) __bf16 bf16x8;
typedef __attribute__((ext_vector_type(4))) __bf16 bf16x4;
typedef __attribute__((ext_vector_type(4))) float f32x4;

#define B_ROWS 16384
#define LDF 2560
#define BN_EPS 1e-5f

__device__ __forceinline__ void async16(void* lds, const void* g) {
  __builtin_amdgcn_global_load_lds(
      (const __attribute__((address_space(1))) unsigned int*)g,
      (__attribute__((address_space(3))) unsigned int*)lds, 16, 0, 0);
}

__device__ __forceinline__ bf16x8 cvt8(float4 a, float4 b) {
  bf16x8 t;
  t[0] = (__bf16)a.x; t[1] = (__bf16)a.y; t[2] = (__bf16)a.z; t[3] = (__bf16)a.w;
  t[4] = (__bf16)b.x; t[5] = (__bf16)b.y; t[6] = (__bf16)b.z; t[7] = (__bf16)b.w;
  return t;
}

// Split-K partial GEMM: Cpart[sk] = A[:, k-slice] x W^T[:, k-slice]
// BM=128 x BN=128, BK=32, 4 waves (2x2), wave-tile 64x64, acc 4x4 (LDS-balanced).
// 4-buffer LDS (64KB -> 2 blocks/CU), prefetch depth 3.
// STAGE = 4 global_load_lds. At loop top tiles t,t+1,t+2 outstanding (12 loads);
// vmcnt(8) completes exactly tile t, keeps t+1,t+2 in flight (verified R6-correct;
// vmcnt(16) is a no-op race -> R8 corruption).
// Grid 1-D with XCD-chunked swizzle (gridDim%8==0): wgid -> (bx, sk, by).
__global__ __launch_bounds__(256, 2) void gemm_sk(
    const __bf16* __restrict__ A, const __bf16* __restrict__ W,
    float* __restrict__ Cpart, int Kd, int Ksplit, int ldc,
    int bxbits, int skbits)
{
  __shared__ __bf16 lds[4][256 * 32];

  const int tid  = threadIdx.x;
  const int lane = tid & 63;
  const int wid  = tid >> 6;
  const int wm   = wid >> 1, wn = wid & 1;
  const int fr   = lane & 15, fk = lane >> 4;

  const int cpx  = gridDim.x >> 3;
  const int wgid = (blockIdx.x & 7) * cpx + (blockIdx.x >> 3);
  const int bx   = wgid & ((1 << bxbits) - 1);
  const int sk   = (wgid >> bxbits) & ((1 << skbits) - 1);
  const int by   = wgid >> (bxbits + skbits);
  const int bn0  = bx * 128, bm0 = by * 128;
  const int k0   = sk * Ksplit;

  // staging: group j (j=0..3) rows j*64+(tid>>2), slot tid&3.
  // Source k-chunk pre-swizzled: LDS[row][slot] holds chunk (slot ^ ((row>>1)&3)).
  const int srow = tid >> 2;
  const int sko  = ((tid & 3) ^ ((tid >> 3) & 3)) << 3;  // elems
  const __bf16* a0p = A + (size_t)(bm0 + srow) * LDF + k0 + sko;
  const __bf16* a1p = a0p + (size_t)64 * LDF;
  const __bf16* b0p = W + (size_t)(bn0 + srow) * Kd + k0 + sko;
  const __bf16* b1p = b0p + (size_t)64 * Kd;

#define STAGE(b, kt) do {                                           \
    async16((void*)(&lds[b][(size_t)tid * 8]),         a0p + (kt)); \
    async16((void*)(&lds[b][(size_t)(256 + tid) * 8]), a1p + (kt)); \
    async16((void*)(&lds[b][(size_t)(512 + tid) * 8]), b0p + (kt)); \
    async16((void*)(&lds[b][(size_t)(768 + tid) * 8]), b1p + (kt)); \
  } while (0)

  // fragment read offsets (loop-invariant): elem = r*32 + (fk ^ ((r>>1)&3))*8
  int aoff[4], boff[4];
#pragma unroll
  for (int i = 0; i < 4; ++i) {
    int ra = wm * 64 + i * 16 + fr;
    aoff[i] = ra * 32 + ((fk ^ ((ra >> 1) & 3)) << 3);
    int rb = wn * 64 + i * 16 + fr;
    boff[i] = 4096 + rb * 32 + ((fk ^ ((rb >> 1) & 3)) << 3);
  }

  f32x4 acc[4][4] = {};

  const int NT = Ksplit >> 5;
  STAGE(0, 0);
  STAGE(1, 32);
  STAGE(2, 64);

  for (int t = 0; t < NT; ++t) {
    if (t <= NT - 3)      asm volatile("s_waitcnt vmcnt(8)" ::: "memory");
    else if (t == NT - 2) asm volatile("s_waitcnt vmcnt(4)" ::: "memory");
    else                  asm volatile("s_waitcnt vmcnt(0)" ::: "memory");
    __builtin_amdgcn_s_barrier();
    __builtin_amdgcn_sched_barrier(0);

    if (t + 3 < NT) STAGE((t + 3) & 3, (t + 3) * 32);
    __builtin_amdgcn_sched_barrier(0);

    const __bf16* bp = lds[t & 3];
    bf16x8 af[4], bf[4];
#pragma unroll
    for (int i = 0; i < 4; ++i) af[i] = *(const bf16x8*)(bp + aoff[i]);
#pragma unroll
    for (int i = 0; i < 4; ++i) bf[i] = *(const bf16x8*)(bp + boff[i]);
#pragma unroll
    for (int mi = 0; mi < 4; ++mi)
#pragma unroll
      for (int ni = 0; ni < 4; ++ni)
        acc[mi][ni] = __builtin_amdgcn_mfma_f32_16x16x32_bf16(af[mi], bf[ni], acc[mi][ni], 0, 0, 0);
  }
#undef STAGE

  float* Cp = Cpart + (size_t)sk * B_ROWS * ldc;
#pragma unroll
  for (int mi = 0; mi < 4; ++mi) {
#pragma unroll
    for (int ni = 0; ni < 4; ++ni) {
      const int row0 = bm0 + wm * 64 + mi * 16 + fk * 4;
      const int col  = bn0 + wn * 64 + ni * 16 + fr;
      float* cp = Cp + (size_t)row0 * ldc + col;
#pragma unroll
      for (int r = 0; r < 4; ++r)
        cp[(size_t)r * ldc] = acc[mi][ni][r];
    }
  }
}

// Stage epilogue: h = relu(Cpart[0]+Cpart[1]+badj) -> bf16 into feats col-block;
// column sum/sumsq accumulated (block-reduced, then global atomics).
// 256 blocks x 64 rows.
__global__ __launch_bounds__(256) void epi_stage(
    const float* __restrict__ Cp, const float* __restrict__ badj,
    __bf16* __restrict__ hout,
    float* __restrict__ colsum, float* __restrict__ colsumsq)
{
  const int tid = threadIdx.x, cg = tid & 63, rg = tid >> 6;
  const int c = cg * 4;
  const int r0 = blockIdx.x * 64 + rg;
  float4 bv = *(const float4*)(badj + c);
  f32x4 ps = {}, pq = {};
#pragma unroll 4
  for (int i = 0; i < 16; ++i) {
    int r = r0 + i * 4;
    const float* p = Cp + (size_t)r * 256 + c;
    float4 a = *(const float4*)p;
    float4 b = *(const float4*)(p + (size_t)B_ROWS * 256);  // sk=1 plane
    float v0 = fmaxf(a.x + b.x + bv.x, 0.f);
    float v1 = fmaxf(a.y + b.y + bv.y, 0.f);
    float v2 = fmaxf(a.z + b.z + bv.z, 0.f);
    float v3 = fmaxf(a.w + b.w + bv.w, 0.f);
    ps[0] += v0; ps[1] += v1; ps[2] += v2; ps[3] += v3;
    pq[0] += v0 * v0; pq[1] += v1 * v1; pq[2] += v2 * v2; pq[3] += v3 * v3;
    bf16x4 o; o[0] = (__bf16)v0; o[1] = (__bf16)v1; o[2] = (__bf16)v2; o[3] = (__bf16)v3;
    *(bf16x4*)(hout + (size_t)r * LDF + c) = o;
  }
  __shared__ f32x4 sred[256], qred[256];
  sred[tid] = ps; qred[tid] = pq;
  __syncthreads();
  if (rg == 0) {
    f32x4 s = sred[cg];
    f32x4 q = qred[cg];
#pragma unroll
    for (int k = 1; k < 4; ++k) {
      f32x4 s2 = sred[k * 64 + cg], q2 = qred[k * 64 + cg];
      s[0] += s2[0]; s[1] += s2[1]; s[2] += s2[2]; s[3] += s2[3];
      q[0] += q2[0]; q[1] += q2[1]; q[2] += q2[2]; q[3] += q2[3];
    }
#pragma unroll
    for (int k = 0; k < 4; ++k) {
      atomicAdd(&colsum[c + k], s[k]);
      atomicAdd(&colsumsq[c + k], q[k]);
    }
  }
}

// Final epilogue: out = sum_{sk<4} Cpart[sk] + badj (fp32, 16384x128)
__global__ __launch_bounds__(256) void epi_final(
    const float* __restrict__ Cp, const float* __restrict__ badj,
    float* __restrict__ out)
{
  int idx = blockIdx.x * 256 + threadIdx.x;   // 524288 threads
  int r = idx >> 5, c = (idx & 31) * 4;
  const float* p = Cp + (size_t)r * 128 + c;
  const size_t pl = (size_t)B_ROWS * 128;
  float4 a = *(const float4*)p;
  float4 b = *(const float4*)(p + pl);
  float4 d2 = *(const float4*)(p + 2 * pl);
  float4 e = *(const float4*)(p + 3 * pl);
  float4 bv = *(const float4*)(badj + c);
  float4 o;
  o.x = a.x + b.x + d2.x + e.x + bv.x;
  o.y = a.y + b.y + d2.y + e.y + bv.y;
  o.z = a.z + b.z + d2.z + e.z + bv.z;
  o.w = a.w + b.w + d2.w + e.w + bv.w;
  *(float4*)(out + (size_t)r * 128 + c) = o;
}

__global__ void cast_x_kernel(const float* __restrict__ x, __bf16* __restrict__ feats) {
  int idx = blockIdx.x * blockDim.x + threadIdx.x;  // B_ROWS*64 threads
  int row = idx >> 6, c8 = (idx & 63) << 3;
  const float4* xp = (const float4*)(x + (size_t)row * 512 + c8);
  float4 a = xp[0], b = xp[1];
  *(bf16x8*)(feats + (size_t)row * LDF + c8) = cvt8(a, b);
}

// Fused fp32->bf16 W-cast with BN folded: W'[n,c]=W[n,c]*sc[c]; badj[n]=bias[n]+sum_c sh[c]*W[n,c]
__global__ void prep_w(const float* __restrict__ W, const float* __restrict__ bias,
                       const float* __restrict__ colsum, const float* __restrict__ colsumsq,
                       const float* __restrict__ gamma, const float* __restrict__ beta,
                       __bf16* __restrict__ Wb, float* __restrict__ badj, int Kd)
{
  const int n = blockIdx.x, t = threadIdx.x;  // 256 threads per row
  const float invB = 1.0f / 16384.0f;
  float accb = 0.f;
  for (int c0 = t * 4; c0 < Kd; c0 += 1024) {
    float4 w = *(const float4*)(W + (size_t)n * Kd + c0);
    float wv[4] = {w.x, w.y, w.z, w.w};
    bf16x4 o;
#pragma unroll
    for (int i = 0; i < 4; ++i) {
      int c = c0 + i;
      float sc = 1.f, sh = 0.f;
      if (c >= 512) {
        int idx = c - 512;
        float mu  = colsum[idx] * invB;
        float var = colsumsq[idx] * invB - mu * mu;
        sc = gamma[idx] * rsqrtf(var + BN_EPS);
        sh = beta[idx] - mu * sc;
      }
      accb += wv[i] * sh;
      o[i] = (__bf16)(wv[i] * sc);
    }
    *(bf16x4*)(Wb + (size_t)n * Kd + c0) = o;
  }
  __shared__ float red[256];
  red[t] = accb;
  __syncthreads();
  for (int s = 128; s > 0; s >>= 1) {
    if (t < s) red[t] += red[t + s];
    __syncthreads();
  }
  if (t == 0) badj[n] = bias[n] + red[0];
}

extern "C" void kernel_launch(void* const* d_in, const int* in_sizes, int n_in,
                              void* d_out, int out_size, void* d_ws, size_t ws_size,
                              hipStream_t stream) {
  const float* x = (const float*)d_in[0];
  const float* Wi[8];
  for (int i = 0; i < 8; ++i) Wi[i] = (const float*)d_in[1 + i];
  const float* b     = (const float*)d_in[9];
  const float* gamma = (const float*)d_in[10];
  const float* beta  = (const float*)d_in[11];
  const float* Wout  = (const float*)d_in[12];
  const float* bout  = (const float*)d_in[13];
  float* out = (float*)d_out;

  char* ws = (char*)d_ws;
  __bf16* feats = (__bf16*)ws;
  size_t off = (size_t)B_ROWS * LDF * 2;
  __bf16* wb[8];
  {
    int d = 512;
    for (int i = 0; i < 8; ++i) { wb[i] = (__bf16*)(ws + off); off += (size_t)256 * d * 2; d += 256; }
  }
  __bf16* woutb = (__bf16*)(ws + off); off += (size_t)128 * 2560 * 2;
  float* Cpart    = (float*)(ws + off); off += (size_t)4 * B_ROWS * 128 * 4;  // 32 MB
  float* colsum   = (float*)(ws + off); off += 8 * 256 * 4;
  float* colsumsq = (float*)(ws + off); off += 8 * 256 * 4;
  float* badj     = (float*)(ws + off); off += 9 * 256 * 4;

  hipMemsetAsync(colsum, 0, 2 * 8 * 256 * 4, stream);

  cast_x_kernel<<<B_ROWS * 64 / 256, 256, 0, stream>>>(x, feats);

  int d = 512;
  for (int i = 0; i < 8; ++i) {
    prep_w<<<256, 256, 0, stream>>>(Wi[i], b + i * 256, colsum, colsumsq,
                                    gamma, beta, wb[i], badj + i * 256, d);
    // SK=2: grid = 2 bx * 2 sk * 128 by = 512 (2 blocks/CU)
    gemm_sk<<<512, 256, 0, stream>>>(feats, wb[i], Cpart, d, d / 2, 256, 1, 1);
    epi_stage<<<256, 256, 0, stream>>>(Cpart, badj + i * 256, feats + d,
                                       colsum + i * 256, colsumsq + i * 256);
    d += 256;
  }
  prep_w<<<128, 256, 0, stream>>>(Wout, bout, colsum, colsumsq,
                                  gamma, beta, woutb, badj + 8 * 256, 2560);
  // final: N=128 (bxbits=0), SK=4: grid = 1 * 4 * 128 = 512
  gemm_sk<<<512, 256, 0, stream>>>(feats, woutb, Cpart, 2560, 640, 128, 0, 2);
  epi_final<<<2048, 256, 0, stream>>>(Cpart, badj + 8 * 256, out);
}

// Round 10
// 337.142 us; speedup vs baseline: 2.6925x; 1.4693x over previous
//
#include <hip/hip_runtime.h>
#include <hip/hip_bf16.h>

typedef __attribute__((ext_vector_type(8))) __bf16 bf16x8;
typedef __attribute__((ext_vector_type(4))) __bf16 bf16x4;
typedef __attribute__((ext_vector_type(4))) float f32x4;

#define B_ROWS 16384
#define LDF 2560
#define BN_EPS 1e-5f

__device__ __forceinline__ void async16(void* lds, const void* g) {
  __builtin_amdgcn_global_load_lds(
      (const __attribute__((address_space(1))) unsigned int*)g,
      (__attribute__((address_space(3))) unsigned int*)lds, 16, 0, 0);
}

__device__ __forceinline__ bf16x8 cvt8(float4 a, float4 b) {
  bf16x8 t;
  t[0] = (__bf16)a.x; t[1] = (__bf16)a.y; t[2] = (__bf16)a.z; t[3] = (__bf16)a.w;
  t[4] = (__bf16)b.x; t[5] = (__bf16)b.y; t[6] = (__bf16)b.z; t[7] = (__bf16)b.w;
  return t;
}

// C-tile = A(bf16,[B_ROWS,LDF]) x W(bf16,[Ntot,Kd])^T (+badj in epilogue)
// BM=64 x BN=128, BK=32, 4 waves (2x2), wave-tile 32x64, acc 2x4.
// 4-buffer LDS (48KB -> 3 blocks/CU), prefetch depth 3.
// STAGE = exactly 3 global_load_lds -> counted vmcnt(6/3/0) keeps 2 tiles in flight.
// Grid 1-D, XCD-chunked swizzle (gridDim%8==0): wgid -> (bx, sk, by).
// mode 1 (skbits=0): h=relu(acc+badj) -> bf16 hout (stride LDF) + col stats atomics.
// mode 0: fp32 partial into Cpart[sk] (ldc=128).
__global__ __launch_bounds__(256) void gemm_stage(
    const __bf16* __restrict__ A, const __bf16* __restrict__ W,
    const float* __restrict__ badj,
    __bf16* __restrict__ hout, float* __restrict__ Cpart,
    float* __restrict__ colsum, float* __restrict__ colsumsq,
    int Kd, int Ksplit, int mode, int bxbits, int skbits)
{
  __shared__ __bf16 lds[4][6144];   // per buf: A 64x32 (2048) + B 128x32 (4096)

  const int tid  = threadIdx.x;
  const int lane = tid & 63;
  const int wid  = tid >> 6;
  const int wm   = wid >> 1, wn = wid & 1;
  const int fr   = lane & 15, fk = lane >> 4;

  const int cpx  = gridDim.x >> 3;
  const int wgid = (blockIdx.x & 7) * cpx + (blockIdx.x >> 3);
  const int bx   = wgid & ((1 << bxbits) - 1);
  const int sk   = (wgid >> bxbits) & ((1 << skbits) - 1);
  const int by   = wgid >> (bxbits + skbits);
  const int bn0  = bx * 128, bm0 = by * 64;
  const int k0   = sk * Ksplit;

  // staging: row = tid>>2 (A; B rows tid>>2 and 64+tid>>2), slot = tid&3.
  // Source k-chunk pre-swizzled: LDS[row][slot] holds chunk (slot ^ ((row>>1)&3)).
  const int srow = tid >> 2;
  const int sko  = ((tid & 3) ^ ((tid >> 3) & 3)) << 3;  // elems
  const __bf16* ap  = A + (size_t)(bm0 + srow) * LDF + k0 + sko;
  const __bf16* b0p = W + (size_t)(bn0 + srow) * Kd + k0 + sko;
  const __bf16* b1p = b0p + (size_t)64 * Kd;

#define STAGE(b, kt) do {                                           \
    async16((void*)(&lds[b][(size_t)tid * 8]),         ap  + (kt)); \
    async16((void*)(&lds[b][(size_t)2048 + tid * 8]),  b0p + (kt)); \
    async16((void*)(&lds[b][(size_t)4096 + tid * 8]),  b1p + (kt)); \
  } while (0)

  // fragment read offsets (loop-invariant): elem = r*32 + (fk ^ ((r>>1)&3))*8
  int aoff[2], boff[4];
#pragma unroll
  for (int i = 0; i < 2; ++i) {
    int ra = wm * 32 + i * 16 + fr;
    aoff[i] = ra * 32 + ((fk ^ ((ra >> 1) & 3)) << 3);
  }
#pragma unroll
  for (int i = 0; i < 4; ++i) {
    int rb = wn * 64 + i * 16 + fr;
    boff[i] = 2048 + rb * 32 + ((fk ^ ((rb >> 1) & 3)) << 3);
  }

  f32x4 acc[2][4] = {};

  const int NT = Ksplit >> 5;
  STAGE(0, 0);
  STAGE(1, 32);
  STAGE(2, 64);

  for (int t = 0; t < NT; ++t) {
    if (t <= NT - 3)      asm volatile("s_waitcnt vmcnt(6)" ::: "memory");
    else if (t == NT - 2) asm volatile("s_waitcnt vmcnt(3)" ::: "memory");
    else                  asm volatile("s_waitcnt vmcnt(0)" ::: "memory");
    __builtin_amdgcn_s_barrier();
    __builtin_amdgcn_sched_barrier(0);

    if (t + 3 < NT) STAGE((t + 3) & 3, (t + 3) * 32);
    __builtin_amdgcn_sched_barrier(0);

    const __bf16* bp = lds[t & 3];
    bf16x8 af[2], bf[4];
#pragma unroll
    for (int i = 0; i < 2; ++i) af[i] = *(const bf16x8*)(bp + aoff[i]);
#pragma unroll
    for (int i = 0; i < 4; ++i) bf[i] = *(const bf16x8*)(bp + boff[i]);
#pragma unroll
    for (int mi = 0; mi < 2; ++mi)
#pragma unroll
      for (int ni = 0; ni < 4; ++ni)
        acc[mi][ni] = __builtin_amdgcn_mfma_f32_16x16x32_bf16(af[mi], bf[ni], acc[mi][ni], 0, 0, 0);
  }
#undef STAGE

  if (mode) {
    float psum[4] = {0.f, 0.f, 0.f, 0.f}, psq[4] = {0.f, 0.f, 0.f, 0.f};
#pragma unroll
    for (int mi = 0; mi < 2; ++mi) {
#pragma unroll
      for (int ni = 0; ni < 4; ++ni) {
        const int col  = bn0 + wn * 64 + ni * 16 + fr;
        const int row0 = bm0 + wm * 32 + mi * 16 + fk * 4;
        const float bv = badj[col];
        __bf16* hp = hout + (size_t)row0 * LDF + col;
#pragma unroll
        for (int r = 0; r < 4; ++r) {
          float v = fmaxf(acc[mi][ni][r] + bv, 0.f);
          psum[ni] += v; psq[ni] += v * v;
          hp[(size_t)r * LDF] = (__bf16)v;
        }
      }
    }
#pragma unroll
    for (int ni = 0; ni < 4; ++ni) {
      float s = psum[ni], q = psq[ni];
      s += __shfl_xor(s, 16); s += __shfl_xor(s, 32);
      q += __shfl_xor(q, 16); q += __shfl_xor(q, 32);
      if (fk == 0) {
        int col = bn0 + wn * 64 + ni * 16 + fr;
        atomicAdd(&colsum[col], s);
        atomicAdd(&colsumsq[col], q);
      }
    }
  } else {
    float* Cp = Cpart + (size_t)sk * B_ROWS * 128;
#pragma unroll
    for (int mi = 0; mi < 2; ++mi) {
#pragma unroll
      for (int ni = 0; ni < 4; ++ni) {
        const int col  = bn0 + wn * 64 + ni * 16 + fr;
        const int row0 = bm0 + wm * 32 + mi * 16 + fk * 4;
        float* cp = Cp + (size_t)row0 * 128 + col;
#pragma unroll
        for (int r = 0; r < 4; ++r)
          cp[(size_t)r * 128] = acc[mi][ni][r];
      }
    }
  }
}

// Final epilogue: out = sum_{sk<4} Cpart[sk] + badj (fp32, 16384x128)
__global__ __launch_bounds__(256) void epi_final(
    const float* __restrict__ Cp, const float* __restrict__ badj,
    float* __restrict__ out)
{
  int idx = blockIdx.x * 256 + threadIdx.x;   // 524288 threads
  int r = idx >> 5, c = (idx & 31) * 4;
  const float* p = Cp + (size_t)r * 128 + c;
  const size_t pl = (size_t)B_ROWS * 128;
  float4 a = *(const float4*)p;
  float4 b = *(const float4*)(p + pl);
  float4 d2 = *(const float4*)(p + 2 * pl);
  float4 e = *(const float4*)(p + 3 * pl);
  float4 bv = *(const float4*)(badj + c);
  float4 o;
  o.x = a.x + b.x + d2.x + e.x + bv.x;
  o.y = a.y + b.y + d2.y + e.y + bv.y;
  o.z = a.z + b.z + d2.z + e.z + bv.z;
  o.w = a.w + b.w + d2.w + e.w + bv.w;
  *(float4*)(out + (size_t)r * 128 + c) = o;
}

__global__ void cast_x_kernel(const float* __restrict__ x, __bf16* __restrict__ feats) {
  int idx = blockIdx.x * blockDim.x + threadIdx.x;  // B_ROWS*64 threads
  int row = idx >> 6, c8 = (idx & 63) << 3;
  const float4* xp = (const float4*)(x + (size_t)row * 512 + c8);
  float4 a = xp[0], b = xp[1];
  *(bf16x8*)(feats + (size_t)row * LDF + c8) = cvt8(a, b);
}

// Fused fp32->bf16 W-cast with BN folded: W'[n,c]=W[n,c]*sc[c]; badj[n]=bias[n]+sum_c sh[c]*W[n,c]
__global__ void prep_w(const float* __restrict__ W, const float* __restrict__ bias,
                       const float* __restrict__ colsum, const float* __restrict__ colsumsq,
                       const float* __restrict__ gamma, const float* __restrict__ beta,
                       __bf16* __restrict__ Wb, float* __restrict__ badj, int Kd)
{
  const int n = blockIdx.x, t = threadIdx.x;  // 256 threads per row
  const float invB = 1.0f / 16384.0f;
  float accb = 0.f;
  for (int c0 = t * 4; c0 < Kd; c0 += 1024) {
    float4 w = *(const float4*)(W + (size_t)n * Kd + c0);
    float wv[4] = {w.x, w.y, w.z, w.w};
    bf16x4 o;
#pragma unroll
    for (int i = 0; i < 4; ++i) {
      int c = c0 + i;
      float sc = 1.f, sh = 0.f;
      if (c >= 512) {
        int idx = c - 512;
        float mu  = colsum[idx] * invB;
        float var = colsumsq[idx] * invB - mu * mu;
        sc = gamma[idx] * rsqrtf(var + BN_EPS);
        sh = beta[idx] - mu * sc;
      }
      accb += wv[i] * sh;
      o[i] = (__bf16)(wv[i] * sc);
    }
    *(bf16x4*)(Wb + (size_t)n * Kd + c0) = o;
  }
  __shared__ float red[256];
  red[t] = accb;
  __syncthreads();
  for (int s = 128; s > 0; s >>= 1) {
    if (t < s) red[t] += red[t + s];
    __syncthreads();
  }
  if (t == 0) badj[n] = bias[n] + red[0];
}

extern "C" void kernel_launch(void* const* d_in, const int* in_sizes, int n_in,
                              void* d_out, int out_size, void* d_ws, size_t ws_size,
                              hipStream_t stream) {
  const float* x = (const float*)d_in[0];
  const float* Wi[8];
  for (int i = 0; i < 8; ++i) Wi[i] = (const float*)d_in[1 + i];
  const float* b     = (const float*)d_in[9];
  const float* gamma = (const float*)d_in[10];
  const float* beta  = (const float*)d_in[11];
  const float* Wout  = (const float*)d_in[12];
  const float* bout  = (const float*)d_in[13];
  float* out = (float*)d_out;

  char* ws = (char*)d_ws;
  __bf16* feats = (__bf16*)ws;
  size_t off = (size_t)B_ROWS * LDF * 2;
  __bf16* wb[8];
  {
    int d = 512;
    for (int i = 0; i < 8; ++i) { wb[i] = (__bf16*)(ws + off); off += (size_t)256 * d * 2; d += 256; }
  }
  __bf16* woutb = (__bf16*)(ws + off); off += (size_t)128 * 2560 * 2;
  float* Cpart    = (float*)(ws + off); off += (size_t)4 * B_ROWS * 128 * 4;  // 32 MB
  float* colsum   = (float*)(ws + off); off += 8 * 256 * 4;
  float* colsumsq = (float*)(ws + off); off += 8 * 256 * 4;
  float* badj     = (float*)(ws + off); off += 9 * 256 * 4;

  hipMemsetAsync(colsum, 0, 2 * 8 * 256 * 4, stream);

  cast_x_kernel<<<B_ROWS * 64 / 256, 256, 0, stream>>>(x, feats);

  int d = 512;
  for (int i = 0; i < 8; ++i) {
    prep_w<<<256, 256, 0, stream>>>(Wi[i], b + i * 256, colsum, colsumsq,
                                    gamma, beta, wb[i], badj + i * 256, d);
    // grid = 2 bx * 256 by = 512 (3 blocks/CU capacity, 2 resident rounds)
    gemm_stage<<<512, 256, 0, stream>>>(feats, wb[i], badj + i * 256,
                                        feats + d, nullptr,
                                        colsum + i * 256, colsumsq + i * 256,
                                        d, d, 1, 1, 0);
    d += 256;
  }
  prep_w<<<128, 256, 0, stream>>>(Wout, bout, colsum, colsumsq,
                                  gamma, beta, woutb, badj + 8 * 256, 2560);
  // final: bxbits=0, SK=4: grid = 1 * 4 * 256 by = 1024
  gemm_stage<<<1024, 256, 0, stream>>>(feats, woutb, nullptr,
                                       nullptr, Cpart, nullptr, nullptr,
                                       2560, 640, 0, 0, 2);
  epi_final<<<2048, 256, 0, stream>>>(Cpart, badj + 8 * 256, out);
}